// Round 15
// baseline (353.366 us; speedup 1.0000x reference)
//
#include <hip/hip_runtime.h>
#include <hip/hip_bf16.h>
#include <math.h>

#define IN_CH 128
#define H_CH  64
#define PBLK  256      // partition blocks (pass A/C grid)
#define PTHR  512      // threads for pass A/C
#define BKT   256      // nodes per bucket
#define MAXBK 400      // max buckets (N <= 102400)

typedef __attribute__((ext_vector_type(8))) short bf16x8;
typedef __attribute__((ext_vector_type(4))) float f32x4;

// ---------------- helpers ----------------

__device__ inline float bflo(unsigned u) { return __uint_as_float(u << 16); }
__device__ inline float bfhi(unsigned u) { return __uint_as_float(u & 0xffff0000u); }
__device__ inline unsigned short f2bf(float f) {   // round-to-nearest-even
    unsigned x = __float_as_uint(f);
    return (unsigned short)((x + 0x7fffu + ((x >> 16) & 1u)) >> 16);
}
__device__ inline bf16x8 pack8(float4 lo, float4 hi) {
    union { bf16x8 v; unsigned short u[8]; } r;
    r.u[0] = f2bf(lo.x); r.u[1] = f2bf(lo.y); r.u[2] = f2bf(lo.z); r.u[3] = f2bf(lo.w);
    r.u[4] = f2bf(hi.x); r.u[5] = f2bf(hi.y); r.u[6] = f2bf(hi.z); r.u[7] = f2bf(hi.w);
    return r.v;
}
__device__ inline float dot8(float4 a0, float4 a1, float4 b0, float4 b1) {
    return a0.x * b0.x + a0.y * b0.y + a0.z * b0.z + a0.w * b0.w
         + a1.x * b1.x + a1.y * b1.y + a1.z * b1.z + a1.w * b1.w;
}
__device__ inline float leakyexp(float a) {   // exp(leaky_relu(a, 0.2))
    return __expf(a > 0.f ? a : 0.2f * a);
}

// ---------------- CSR build: bucket partition, LDS atomics only ----------------

__global__ __launch_bounds__(PTHR) void passA(const int* __restrict__ ei, int E, int n,
                                              int nbk, int* __restrict__ blkhist) {
    __shared__ int hist[MAXBK];
    int tot = E + n;
    int CH = (tot + gridDim.x - 1) / gridDim.x;
    int beg = blockIdx.x * CH, end = min(tot, beg + CH);
    for (int k = threadIdx.x; k < nbk; k += blockDim.x) hist[k] = 0;
    __syncthreads();
    for (int idx = beg + threadIdx.x; idx < end; idx += blockDim.x) {
        int d = (idx < E) ? ei[E + idx] : (idx - E);
        atomicAdd(&hist[d >> 8], 1);
    }
    __syncthreads();
    for (int k = threadIdx.x; k < nbk; k += blockDim.x)
        blkhist[(size_t)blockIdx.x * nbk + k] = hist[k];
}

__global__ __launch_bounds__(PBLK) void passB1(const int* __restrict__ blkhist,
                                               int* __restrict__ blkbase,
                                               int* __restrict__ btot, int nbk) {
    __shared__ int sh[PBLK];
    int k = blockIdx.x, t = threadIdx.x;
    int v = blkhist[(size_t)t * nbk + k];
    sh[t] = v;
    __syncthreads();
    for (int off = 1; off < PBLK; off <<= 1) {
        int x = (t >= off) ? sh[t - off] : 0;
        __syncthreads();
        sh[t] += x;
        __syncthreads();
    }
    blkbase[(size_t)t * nbk + k] = sh[t] - v;
    if (t == PBLK - 1) btot[k] = sh[PBLK - 1];
}

__global__ __launch_bounds__(PTHR) void passC(const int* __restrict__ ei, int E, int n, int nbk,
                                              const int* __restrict__ btot,
                                              const int* __restrict__ blkbase,
                                              int2* __restrict__ pairs) {
    __shared__ int cur[MAXBK];
    __shared__ int sc[PTHR];
    int t = threadIdx.x;
    int v = (t < nbk) ? btot[t] : 0;
    sc[t] = v;
    __syncthreads();
    for (int off = 1; off < PTHR; off <<= 1) {
        int x = (t >= off) ? sc[t - off] : 0;
        __syncthreads();
        sc[t] += x;
        __syncthreads();
    }
    if (t < nbk) cur[t] = (sc[t] - v) + blkbase[(size_t)blockIdx.x * nbk + t];
    __syncthreads();

    int tot = E + n;
    int CH = (tot + gridDim.x - 1) / gridDim.x;
    int beg = blockIdx.x * CH, end = min(tot, beg + CH);
    for (int idx = beg + t; idx < end; idx += blockDim.x) {
        int s, d;
        if (idx < E) { s = ei[idx]; d = ei[E + idx]; }
        else         { s = idx - E; d = idx - E; }
        int pos = atomicAdd(&cur[d >> 8], 1);
        pairs[pos] = make_int2(s, d);
    }
}

__global__ __launch_bounds__(BKT) void passD(const int2* __restrict__ pairs,
                                             const int* __restrict__ btot, int n, int nbk, int EP,
                                             int* __restrict__ esrc, int* __restrict__ offsets,
                                             float* __restrict__ dinv) {
    __shared__ int cnt[BKT];
    __shared__ int sh[BKT];
    __shared__ int cur[BKT];
    __shared__ int red[BKT];
    int k = blockIdx.x;
    int nbeg = k << 8;
    int t = threadIdx.x;

    int part = 0;
    for (int j = t; j < k; j += BKT) part += btot[j];
    red[t] = part;
    __syncthreads();
    for (int off = BKT / 2; off; off >>= 1) {
        if (t < off) red[t] += red[t + off];
        __syncthreads();
    }
    int ebeg = red[0];
    int eend = ebeg + btot[k];

    cnt[t] = 0;
    __syncthreads();
    for (int e = ebeg + t; e < eend; e += BKT) {
        int2 p = pairs[e];
        atomicAdd(&cnt[p.y - nbeg], 1);
    }
    __syncthreads();
    int v = cnt[t];
    sh[t] = v;
    __syncthreads();
    for (int off = 1; off < BKT; off <<= 1) {
        int x = (t >= off) ? sh[t - off] : 0;
        __syncthreads();
        sh[t] += x;
        __syncthreads();
    }
    int lp = sh[t] - v;
    cur[t] = lp;
    int gn = nbeg + t;
    if (gn < n) {
        offsets[gn] = ebeg + lp;
        dinv[gn] = rsqrtf((float)v);
    }
    __syncthreads();
    for (int e = ebeg + t; e < eend; e += BKT) {
        int2 p = pairs[e];
        int pos = ebeg + atomicAdd(&cur[p.y - nbeg], 1);
        esrc[pos] = p.x;
    }
    if (k == 0 && t == 0) offsets[n] = EP;
}

// ---------------- per-edge weight precompute (node-parallel) --------------------
// wedge = p_e / sum_e p_e  (EXACT reference GAT alpha formula)
// wnorm = dinv[src] * dinv[dst]  (EXACT reference GCN norm formula)

__global__ __launch_bounds__(256) void wprep_edges(const int* __restrict__ offs,
                                                   const int* __restrict__ esrc,
                                                   const float* __restrict__ as,
                                                   const float* __restrict__ ad,
                                                   const float* __restrict__ dinv,
                                                   float* __restrict__ wedge,
                                                   float* __restrict__ wnorm, int n) {
    int lane = threadIdx.x & 63;
    int gw = (blockIdx.x * blockDim.x + threadIdx.x) >> 6;
    int nw = (gridDim.x * blockDim.x) >> 6;
    for (int i = gw; i < n; i += nw) {
        int beg = offs[i], end = offs[i + 1];
        float adi = ad[i], di = dinv[i];
        float s = 0.f;
        for (int base = beg; base < end; base += 64) {
            int l = base + lane;
            if (l < end) s += leakyexp(as[esrc[l]] + adi);
        }
#pragma unroll
        for (int off = 1; off < 64; off <<= 1) s += __shfl_xor(s, off, 64);
        float invs = 1.f / (s + 1e-16f);
        for (int base = beg; base < end; base += 64) {
            int l = base + lane;
            if (l < end) {
                int sj = esrc[l];
                wedge[l] = leakyexp(as[sj] + adi) * invs;
                wnorm[l] = dinv[sj] * di;
            }
        }
    }
}

// ---------------- slab gather: slice q = blockIdx&3 -> one 16-ch slab (3.2MB, fits
// per-XCD L2; round-robin blockIdx->XCD pins slice to XCD). Weights precomputed ->
// gather is a pure weighted sum. LDS staging kept (r13: essential). r11/r12/r14 all
// walled at ~43us on L2-miss service for 12.8MB random rows; slabs make them hits.

template <bool RELU, bool BIAS>
__global__ __launch_bounds__(256) void slab_gather(const unsigned short* __restrict__ hs,
                                                   const int* __restrict__ offs,
                                                   const int* __restrict__ esrc,
                                                   const float* __restrict__ w,
                                                   const float* __restrict__ bias,
                                                   unsigned short* __restrict__ outs, int n) {
    __shared__ int2 sh[4][64];
    int lane = threadIdx.x & 63;
    int wid  = threadIdx.x >> 6;
    int q  = blockIdx.x & 3;
    size_t qn = (size_t)q * n;
    int e8 = lane >> 3, c2 = lane & 7;
    int g  = (blockIdx.x >> 2) * 4 + wid;
    int nw = (gridDim.x >> 2) * 4;
    float2 bv = {0.f, 0.f};
    if (BIAS) bv = *(const float2*)(bias + q * 16 + 2 * c2);
    for (int i = g; i < n; i += nw) {
        int beg = offs[i], end = offs[i + 1];
        float2 A = {0.f, 0.f};
        for (int base = beg; base < end; base += 64) {
            int l = base + lane;
            int sj = 0; float wl = 0.f;
            if (l < end) { sj = esrc[l]; wl = w[l]; }
            sh[wid][lane] = make_int2(sj, __float_as_int(wl));
            int cnt = min(64, end - base);
            int k = 0;
            for (; k + 16 <= cnt; k += 16) {
                int2 t0 = sh[wid][k + e8];
                int2 t1 = sh[wid][k + 8 + e8];
                float p0 = __int_as_float(t0.y), p1 = __int_as_float(t1.y);
                unsigned u0 = *(const unsigned*)(hs + (qn + (unsigned)t0.x) * 16 + 2 * c2);
                unsigned u1 = *(const unsigned*)(hs + (qn + (unsigned)t1.x) * 16 + 2 * c2);
                A.x += p0 * bflo(u0); A.y += p0 * bfhi(u0);
                A.x += p1 * bflo(u1); A.y += p1 * bfhi(u1);
            }
            for (; k < cnt; k += 8) {             // zero-padded entries safe
                int2 t0 = sh[wid][k + e8];
                float p0 = __int_as_float(t0.y);
                unsigned u0 = *(const unsigned*)(hs + (qn + (unsigned)t0.x) * 16 + 2 * c2);
                A.x += p0 * bflo(u0); A.y += p0 * bfhi(u0);
            }
        }
        A.x += __shfl_xor(A.x, 8, 64);  A.y += __shfl_xor(A.y, 8, 64);
        A.x += __shfl_xor(A.x, 16, 64); A.y += __shfl_xor(A.y, 16, 64);
        A.x += __shfl_xor(A.x, 32, 64); A.y += __shfl_xor(A.y, 32, 64);
        if (e8 == 0) {
            float v0 = A.x + bv.x, v1 = A.y + bv.y;
            if (RELU) { v0 = fmaxf(v0, 0.f); v1 = fmaxf(v1, 0.f); }
            *(unsigned*)(outs + (qn + i) * 16 + 2 * c2) =
                (unsigned)f2bf(v0) | ((unsigned)f2bf(v1) << 16);
        }
    }
}

// ---------------- MFMA GEMM: wave = 16-row strip x 64 cols, 16x16x32 bf16 --------------
// TIN=float: row-major fp32 input (layer 1). TIN=ushort: slab bf16 input
// ([4][n][16ch]; an 8-ch A-fragment chunk never straddles a slab). OUTBF writes slab;
// else row-major fp32 (final out). GAT alphas from fp32 X dot (W@att, LDS) -> exact.

template <int K, bool GAT, bool OUTBF, bool BIASF, typename TIN>
__global__ __launch_bounds__(256) void mfma_gemm(const TIN* __restrict__ X,
                                                 const float* __restrict__ W,
                                                 void* __restrict__ outv,
                                                 const float* __restrict__ att_s,
                                                 const float* __restrict__ att_d,
                                                 float* __restrict__ alpha_s,
                                                 float* __restrict__ alpha_d,
                                                 const float* __restrict__ bias, int n) {
    constexpr int KF = K / 32;
    __shared__ __align__(16) float swas[K];
    __shared__ __align__(16) float swad[K];
    if (GAT) {
        if (threadIdx.x < K) {
            float s = 0.f, d = 0.f;
            for (int cc = 0; cc < H_CH; cc++) {
                float w = W[(size_t)threadIdx.x * H_CH + cc];
                s += w * att_s[cc];
                d += w * att_d[cc];
            }
            swas[threadIdx.x] = s;
            swad[threadIdx.x] = d;
        }
        __syncthreads();
    }

    int lane = threadIdx.x & 63;
    int wid  = threadIdx.x >> 6;
    int col  = lane & 15;
    int grp  = lane >> 4;

    bf16x8 bfr[KF][4];
#pragma unroll
    for (int kf = 0; kf < KF; kf++) {
        int kb = 32 * kf + 8 * grp;
#pragma unroll
        for (int cf = 0; cf < 4; cf++) {
            float w0[8];
#pragma unroll
            for (int e = 0; e < 8; e++)
                w0[e] = W[(size_t)(kb + e) * H_CH + 16 * cf + col];
            bfr[kf][cf] = pack8(make_float4(w0[0], w0[1], w0[2], w0[3]),
                                make_float4(w0[4], w0[5], w0[6], w0[7]));
        }
    }
    float bb[4] = {0.f, 0.f, 0.f, 0.f};
    if (BIASF) {
#pragma unroll
        for (int cf = 0; cf < 4; cf++) bb[cf] = bias[16 * cf + col];
    }

    int gw = blockIdx.x * (blockDim.x >> 6) + wid;
    int nw = gridDim.x * (blockDim.x >> 6);
    int ns = (n + 15) >> 4;
    for (int s = gw; s < ns; s += nw) {
        int r0 = s << 4;
        int r  = r0 + col;
        int rc = r < n ? r : 0;
        bf16x8 afr[KF];
        float ps = 0.f, pd = 0.f;
#pragma unroll
        for (int kf = 0; kf < KF; kf++) {
            int kb = 32 * kf + 8 * grp;
            if constexpr (sizeof(TIN) == 2) {
                // slab read: slab kb>>4, within-slab channel kb&15 (0 or 8)
                afr[kf] = *(const bf16x8*)(X + ((size_t)(kb >> 4) * n + rc) * 16 + (kb & 15));
            } else {
                const TIN* xr = X + (size_t)rc * K;
                float4 x0 = *(const float4*)(xr + kb);
                float4 x1 = *(const float4*)(xr + kb + 4);
                if (GAT) {
                    float4 s0 = *(const float4*)(swas + kb);
                    float4 s1 = *(const float4*)(swas + kb + 4);
                    float4 d0 = *(const float4*)(swad + kb);
                    float4 d1 = *(const float4*)(swad + kb + 4);
                    ps += dot8(x0, x1, s0, s1);
                    pd += dot8(x0, x1, d0, d1);
                }
                afr[kf] = pack8(x0, x1);
            }
        }
        f32x4 acc[4];
#pragma unroll
        for (int cf = 0; cf < 4; cf++) {
            acc[cf] = (f32x4){0.f, 0.f, 0.f, 0.f};
#pragma unroll
            for (int kf = 0; kf < KF; kf++)
                acc[cf] = __builtin_amdgcn_mfma_f32_16x16x32_bf16(afr[kf], bfr[kf][cf],
                                                                  acc[cf], 0, 0, 0);
        }
#pragma unroll
        for (int cf = 0; cf < 4; cf++) {
            int cc = 16 * cf + col;
#pragma unroll
            for (int g = 0; g < 4; g++) {
                int rr = r0 + 4 * grp + g;
                if (rr < n) {
                    float v = acc[cf][g] + bb[cf];
                    if (OUTBF)   // slab write: slab cf, channel col
                        ((unsigned short*)outv)[((size_t)cf * n + rr) * 16 + col] = f2bf(v);
                    else
                        ((float*)outv)[(size_t)rr * H_CH + cc] = v;
                }
            }
        }
        if (GAT) {
            ps += __shfl_xor(ps, 16, 64); ps += __shfl_xor(ps, 32, 64);
            pd += __shfl_xor(pd, 16, 64); pd += __shfl_xor(pd, 32, 64);
            if (grp == 0 && r < n) { alpha_s[r] = ps; alpha_d[r] = pd; }
        }
    }
}

// ---------------- launch ----------------

extern "C" void kernel_launch(void* const* d_in, const int* in_sizes, int n_in,
                              void* d_out, int out_size, void* d_ws, size_t ws_size,
                              hipStream_t stream) {
    const float* x       = (const float*)d_in[0];
    const int*   ei      = (const int*)d_in[1];
    const float* W_gat   = (const float*)d_in[2];
    const float* att_src = (const float*)d_in[3];
    const float* att_dst = (const float*)d_in[4];
    const float* b_gat   = (const float*)d_in[5];
    const float* W1      = (const float*)d_in[6];
    const float* b1      = (const float*)d_in[7];
    const float* W2      = (const float*)d_in[8];
    const float* b2      = (const float*)d_in[9];
    float* out = (float*)d_out;

    const int N  = in_sizes[0] / IN_CH;
    const int E  = in_sizes[1] / 2;
    const int EP = E + N;
    const int NBK = (N + BKT - 1) / BKT;

    char* p = (char*)d_ws;
    auto alloc = [&](size_t bytes) -> void* {
        void* r = (void*)p;
        p += (bytes + 255) & ~(size_t)255;
        return r;
    };
    unsigned short* hbf  = (unsigned short*)alloc((size_t)N * H_CH * 2);  // slab: gemm1/2 out
    unsigned short* hbfA = (unsigned short*)alloc((size_t)N * H_CH * 2);  // slab: gat out / agg3
    unsigned short* hbf2 = (unsigned short*)alloc((size_t)N * H_CH * 2);  // slab: gather2 out
    float* alpha_s = (float*)alloc((size_t)N * 4);
    float* alpha_d = (float*)alloc((size_t)N * 4);
    float* dinv    = (float*)alloc((size_t)N * 4);
    float* wedge   = (float*)alloc((size_t)EP * 4);
    float* wnorm   = (float*)alloc((size_t)EP * 4);
    int*   offsets = (int*)alloc((size_t)(N + 1) * 4);
    int*   esrc    = (int*)alloc((size_t)EP * 4);
    int2*  pairs   = (int2*)alloc((size_t)EP * 8);
    int*   blkhist = (int*)alloc((size_t)PBLK * NBK * 4);
    int*   blkbase = (int*)alloc((size_t)PBLK * NBK * 4);
    int*   btot    = (int*)alloc((size_t)(NBK + 1) * 4);

    // CSR build (no global atomics, no memsets)
    passA<<<PBLK, PTHR, 0, stream>>>(ei, E, N, NBK, blkhist);
    passB1<<<NBK, PBLK, 0, stream>>>(blkhist, blkbase, btot, NBK);
    passC<<<PBLK, PTHR, 0, stream>>>(ei, E, N, NBK, btot, blkbase, pairs);
    passD<<<NBK, BKT, 0, stream>>>(pairs, btot, N, NBK, EP, esrc, offsets, dinv);

    // layer 1 GEMM: fp32 x -> bf16 slab h + fp32 alphas
    mfma_gemm<IN_CH, true, true, false, float><<<512, 256, 0, stream>>>(
        x, W_gat, hbf, att_src, att_dst, alpha_s, alpha_d, nullptr, N);

    // per-edge weights (GAT normalized alphas + GCN norm), once for all gathers
    wprep_edges<<<2048, 256, 0, stream>>>(offsets, esrc, alpha_s, alpha_d, dinv,
                                          wedge, wnorm, N);

    // layer 1 gather (GAT): slab h -> slab hbfA, +bias, relu
    slab_gather<true, true><<<2048, 256, 0, stream>>>(hbf, offsets, esrc, wedge,
                                                      b_gat, hbfA, N);

    // layer 2: GEMM (slab in -> slab out), gather (+b1, relu) -> slab hbf2
    mfma_gemm<H_CH, false, true, false, unsigned short><<<512, 256, 0, stream>>>(
        hbfA, W1, hbf, nullptr, nullptr, nullptr, nullptr, nullptr, N);
    slab_gather<true, true><<<2048, 256, 0, stream>>>(hbf, offsets, esrc, wnorm,
                                                      b1, hbf2, N);

    // layer 3 reordered: agg3 = A_norm h2 (slab), out = agg3 @ W2 + b2 (row-major fp32)
    slab_gather<false, false><<<2048, 256, 0, stream>>>(hbf2, offsets, esrc, wnorm,
                                                        nullptr, hbfA, N);
    mfma_gemm<H_CH, false, false, true, unsigned short><<<512, 256, 0, stream>>>(
        hbfA, W2, out, nullptr, nullptr, nullptr, nullptr, b2, N);
}

// Round 16
// 201.821 us; speedup vs baseline: 1.7509x; 1.7509x over previous
//
#include <hip/hip_runtime.h>
#include <hip/hip_bf16.h>
#include <math.h>

#define IN_CH 128
#define H_CH  64
#define PBLK  256      // partition blocks (pass A/C grid)
#define PTHR  512      // threads for pass A/C
#define BKT   256      // nodes per bucket
#define MAXBK 400      // max buckets (N <= 102400)

typedef __attribute__((ext_vector_type(8))) short bf16x8;
typedef __attribute__((ext_vector_type(4))) float f32x4;

// ---------------- helpers ----------------

__device__ inline float bflo(unsigned u) { return __uint_as_float(u << 16); }
__device__ inline float bfhi(unsigned u) { return __uint_as_float(u & 0xffff0000u); }
__device__ inline unsigned short f2bf(float f) {   // round-to-nearest-even
    unsigned x = __float_as_uint(f);
    return (unsigned short)((x + 0x7fffu + ((x >> 16) & 1u)) >> 16);
}
__device__ inline bf16x8 pack8(float4 lo, float4 hi) {
    union { bf16x8 v; unsigned short u[8]; } r;
    r.u[0] = f2bf(lo.x); r.u[1] = f2bf(lo.y); r.u[2] = f2bf(lo.z); r.u[3] = f2bf(lo.w);
    r.u[4] = f2bf(hi.x); r.u[5] = f2bf(hi.y); r.u[6] = f2bf(hi.z); r.u[7] = f2bf(hi.w);
    return r.v;
}
__device__ inline float dot8(float4 a0, float4 a1, float4 b0, float4 b1) {
    return a0.x * b0.x + a0.y * b0.y + a0.z * b0.z + a0.w * b0.w
         + a1.x * b1.x + a1.y * b1.y + a1.z * b1.z + a1.w * b1.w;
}
__device__ inline float leakyexp(float a) {   // exp(leaky_relu(a, 0.2))
    return __expf(a > 0.f ? a : 0.2f * a);
}

// ---------------- CSR build: bucket partition, LDS atomics only ----------------

__global__ __launch_bounds__(PTHR) void passA(const int* __restrict__ ei, int E, int n,
                                              int nbk, int* __restrict__ blkhist) {
    __shared__ int hist[MAXBK];
    int tot = E + n;
    int CH = (tot + gridDim.x - 1) / gridDim.x;
    int beg = blockIdx.x * CH, end = min(tot, beg + CH);
    for (int k = threadIdx.x; k < nbk; k += blockDim.x) hist[k] = 0;
    __syncthreads();
    for (int idx = beg + threadIdx.x; idx < end; idx += blockDim.x) {
        int d = (idx < E) ? ei[E + idx] : (idx - E);
        atomicAdd(&hist[d >> 8], 1);
    }
    __syncthreads();
    for (int k = threadIdx.x; k < nbk; k += blockDim.x)
        blkhist[(size_t)blockIdx.x * nbk + k] = hist[k];
}

__global__ __launch_bounds__(PBLK) void passB1(const int* __restrict__ blkhist,
                                               int* __restrict__ blkbase,
                                               int* __restrict__ btot, int nbk) {
    __shared__ int sh[PBLK];
    int k = blockIdx.x, t = threadIdx.x;
    int v = blkhist[(size_t)t * nbk + k];
    sh[t] = v;
    __syncthreads();
    for (int off = 1; off < PBLK; off <<= 1) {
        int x = (t >= off) ? sh[t - off] : 0;
        __syncthreads();
        sh[t] += x;
        __syncthreads();
    }
    blkbase[(size_t)t * nbk + k] = sh[t] - v;
    if (t == PBLK - 1) btot[k] = sh[PBLK - 1];
}

// passC: btot scan folded in (passB2 kernel removed, r13-proven)
__global__ __launch_bounds__(PTHR) void passC(const int* __restrict__ ei, int E, int n, int nbk,
                                              const int* __restrict__ btot,
                                              const int* __restrict__ blkbase,
                                              int2* __restrict__ pairs) {
    __shared__ int cur[MAXBK];
    __shared__ int sc[PTHR];
    int t = threadIdx.x;
    int v = (t < nbk) ? btot[t] : 0;
    sc[t] = v;
    __syncthreads();
    for (int off = 1; off < PTHR; off <<= 1) {
        int x = (t >= off) ? sc[t - off] : 0;
        __syncthreads();
        sc[t] += x;
        __syncthreads();
    }
    if (t < nbk) cur[t] = (sc[t] - v) + blkbase[(size_t)blockIdx.x * nbk + t];
    __syncthreads();

    int tot = E + n;
    int CH = (tot + gridDim.x - 1) / gridDim.x;
    int beg = blockIdx.x * CH, end = min(tot, beg + CH);
    for (int idx = beg + t; idx < end; idx += blockDim.x) {
        int s, d;
        if (idx < E) { s = ei[idx]; d = ei[E + idx]; }
        else         { s = idx - E; d = idx - E; }
        int pos = atomicAdd(&cur[d >> 8], 1);
        pairs[pos] = make_int2(s, d);
    }
}

// passD: bucket bounds derived from btot reduce (r13-proven)
__global__ __launch_bounds__(BKT) void passD(const int2* __restrict__ pairs,
                                             const int* __restrict__ btot, int n, int nbk, int EP,
                                             int* __restrict__ esrc, int* __restrict__ offsets,
                                             float* __restrict__ dinv) {
    __shared__ int cnt[BKT];
    __shared__ int sh[BKT];
    __shared__ int cur[BKT];
    __shared__ int red[BKT];
    int k = blockIdx.x;
    int nbeg = k << 8;
    int t = threadIdx.x;

    int part = 0;
    for (int j = t; j < k; j += BKT) part += btot[j];
    red[t] = part;
    __syncthreads();
    for (int off = BKT / 2; off; off >>= 1) {
        if (t < off) red[t] += red[t + off];
        __syncthreads();
    }
    int ebeg = red[0];
    int eend = ebeg + btot[k];

    cnt[t] = 0;
    __syncthreads();
    for (int e = ebeg + t; e < eend; e += BKT) {
        int2 p = pairs[e];
        atomicAdd(&cnt[p.y - nbeg], 1);
    }
    __syncthreads();
    int v = cnt[t];
    sh[t] = v;
    __syncthreads();
    for (int off = 1; off < BKT; off <<= 1) {
        int x = (t >= off) ? sh[t - off] : 0;
        __syncthreads();
        sh[t] += x;
        __syncthreads();
    }
    int lp = sh[t] - v;
    cur[t] = lp;
    int gn = nbeg + t;
    if (gn < n) {
        offsets[gn] = ebeg + lp;
        dinv[gn] = rsqrtf((float)v);
    }
    __syncthreads();
    for (int e = ebeg + t; e < eend; e += BKT) {
        int2 p = pairs[e];
        int pos = ebeg + atomicAdd(&cur[p.y - nbeg], 1);
        esrc[pos] = p.x;
    }
    if (k == 0 && t == 0) offsets[n] = EP;
}

// ---------------- MFMA GEMM: wave = 16-row strip x 64 cols, 16x16x32 bf16 --------------
// r14-measured version: TIN=float packs fp32->bf16 in-register (RNE); TIN=ushort direct.
// GAT: per-block LDS precompute of w_as = W@att_src, w_ad = W@att_dst (wprep folded);
// alphas from fp32 X dot these -> exact (r4 lesson). Layouts m89-verified.

template <int K, bool GAT, bool OUTBF, bool BIASF, typename TIN>
__global__ __launch_bounds__(256) void mfma_gemm(const TIN* __restrict__ X,
                                                 const float* __restrict__ W,
                                                 void* __restrict__ outv,
                                                 const float* __restrict__ att_s,
                                                 const float* __restrict__ att_d,
                                                 float* __restrict__ alpha_s,
                                                 float* __restrict__ alpha_d,
                                                 const float* __restrict__ bias, int n) {
    constexpr int KF = K / 32;
    __shared__ __align__(16) float swas[K];
    __shared__ __align__(16) float swad[K];
    if (GAT) {
        if (threadIdx.x < K) {
            float s = 0.f, d = 0.f;
            for (int cc = 0; cc < H_CH; cc++) {
                float w = W[(size_t)threadIdx.x * H_CH + cc];
                s += w * att_s[cc];
                d += w * att_d[cc];
            }
            swas[threadIdx.x] = s;
            swad[threadIdx.x] = d;
        }
        __syncthreads();
    }

    int lane = threadIdx.x & 63;
    int wid  = threadIdx.x >> 6;
    int col  = lane & 15;
    int grp  = lane >> 4;

    bf16x8 bfr[KF][4];
#pragma unroll
    for (int kf = 0; kf < KF; kf++) {
        int kb = 32 * kf + 8 * grp;
#pragma unroll
        for (int cf = 0; cf < 4; cf++) {
            float w0[8];
#pragma unroll
            for (int e = 0; e < 8; e++)
                w0[e] = W[(size_t)(kb + e) * H_CH + 16 * cf + col];
            bfr[kf][cf] = pack8(make_float4(w0[0], w0[1], w0[2], w0[3]),
                                make_float4(w0[4], w0[5], w0[6], w0[7]));
        }
    }
    float bb[4] = {0.f, 0.f, 0.f, 0.f};
    if (BIASF) {
#pragma unroll
        for (int cf = 0; cf < 4; cf++) bb[cf] = bias[16 * cf + col];
    }

    int gw = blockIdx.x * (blockDim.x >> 6) + wid;
    int nw = gridDim.x * (blockDim.x >> 6);
    int ns = (n + 15) >> 4;
    for (int s = gw; s < ns; s += nw) {
        int r0 = s << 4;
        int r  = r0 + col;
        const TIN* xr = X + (size_t)(r < n ? r : 0) * K;
        bf16x8 afr[KF];
        float ps = 0.f, pd = 0.f;
#pragma unroll
        for (int kf = 0; kf < KF; kf++) {
            int kb = 32 * kf + 8 * grp;
            if constexpr (sizeof(TIN) == 2) {
                afr[kf] = *(const bf16x8*)(xr + kb);
            } else {
                float4 x0 = *(const float4*)(xr + kb);
                float4 x1 = *(const float4*)(xr + kb + 4);
                if (GAT) {
                    float4 s0 = *(const float4*)(swas + kb);
                    float4 s1 = *(const float4*)(swas + kb + 4);
                    float4 d0 = *(const float4*)(swad + kb);
                    float4 d1 = *(const float4*)(swad + kb + 4);
                    ps += dot8(x0, x1, s0, s1);
                    pd += dot8(x0, x1, d0, d1);
                }
                afr[kf] = pack8(x0, x1);
            }
        }
        f32x4 acc[4];
#pragma unroll
        for (int cf = 0; cf < 4; cf++) {
            acc[cf] = (f32x4){0.f, 0.f, 0.f, 0.f};
#pragma unroll
            for (int kf = 0; kf < KF; kf++)
                acc[cf] = __builtin_amdgcn_mfma_f32_16x16x32_bf16(afr[kf], bfr[kf][cf],
                                                                  acc[cf], 0, 0, 0);
        }
#pragma unroll
        for (int cf = 0; cf < 4; cf++) {
            int cc = 16 * cf + col;
#pragma unroll
            for (int g = 0; g < 4; g++) {
                int rr = r0 + 4 * grp + g;
                if (rr < n) {
                    float v = acc[cf][g] + bb[cf];
                    if (OUTBF) ((unsigned short*)outv)[(size_t)rr * H_CH + cc] = f2bf(v);
                    else       ((float*)outv)[(size_t)rr * H_CH + cc] = v;
                }
            }
        }
        if (GAT) {
            ps += __shfl_xor(ps, 16, 64); ps += __shfl_xor(ps, 32, 64);
            pd += __shfl_xor(pd, 16, 64); pd += __shfl_xor(pd, 32, 64);
            if (grp == 0 && r < n) { alpha_s[r] = ps; alpha_d[r] = pd; }
        }
    }
}

// ---------------- GAT gather: r12's fastest-measured variant (43.6us) ----------------
// LDS-staged (r13: staging essential; r15: slicing x4 per-node overhead fails at deg~17).
// Quarter-wave lanes: (q, c=0..15), uint2 (4ch) rows, 16 edges/iter (4 loads in flight).
// Single-pass unnormalized softmax (|e| bounded -> exact); bf16 out (identical f2bf).

__global__ __launch_bounds__(256) void gat_gather(const unsigned short* __restrict__ h,
                                                  const int* __restrict__ offs,
                                                  const int* __restrict__ esrc,
                                                  const float* __restrict__ as,
                                                  const float* __restrict__ ad,
                                                  const float* __restrict__ bias,
                                                  unsigned short* __restrict__ out, int n) {
    __shared__ int2 sh[4][64];
    int lane = threadIdx.x & 63;
    int wid  = threadIdx.x >> 6;
    int q = lane >> 4, c = lane & 15;
    int gw = (blockIdx.x * blockDim.x + threadIdx.x) >> 6;
    int nw = (gridDim.x * blockDim.x) >> 6;
    float4 bv = *(const float4*)(bias + 4 * c);
    for (int i = gw; i < n; i += nw) {
        int beg = offs[i], end = offs[i + 1];
        float adi = ad[i];
        float a0 = 0.f, a1 = 0.f, a2 = 0.f, a3 = 0.f, s = 0.f;
        for (int base = beg; base < end; base += 64) {
            int l = base + lane;
            int sj = 0; float p = 0.f;
            if (l < end) { sj = esrc[l]; p = leakyexp(as[sj] + adi); }
            sh[wid][lane] = make_int2(sj, __float_as_int(p));
            int cnt = min(64, end - base);
            int k = 0;
            for (; k + 16 <= cnt; k += 16) {
                int2 t0 = sh[wid][k + q];
                int2 t1 = sh[wid][k + 4 + q];
                int2 t2 = sh[wid][k + 8 + q];
                int2 t3 = sh[wid][k + 12 + q];
                float p0 = __int_as_float(t0.y), p1 = __int_as_float(t1.y);
                float p2 = __int_as_float(t2.y), p3 = __int_as_float(t3.y);
                uint2 u0 = *(const uint2*)(h + (size_t)t0.x * H_CH + 4 * c);
                uint2 u1 = *(const uint2*)(h + (size_t)t1.x * H_CH + 4 * c);
                uint2 u2 = *(const uint2*)(h + (size_t)t2.x * H_CH + 4 * c);
                uint2 u3 = *(const uint2*)(h + (size_t)t3.x * H_CH + 4 * c);
                a0 += p0 * bflo(u0.x); a1 += p0 * bfhi(u0.x);
                a2 += p0 * bflo(u0.y); a3 += p0 * bfhi(u0.y);
                a0 += p1 * bflo(u1.x); a1 += p1 * bfhi(u1.x);
                a2 += p1 * bflo(u1.y); a3 += p1 * bfhi(u1.y);
                a0 += p2 * bflo(u2.x); a1 += p2 * bfhi(u2.x);
                a2 += p2 * bflo(u2.y); a3 += p2 * bfhi(u2.y);
                a0 += p3 * bflo(u3.x); a1 += p3 * bfhi(u3.x);
                a2 += p3 * bflo(u3.y); a3 += p3 * bfhi(u3.y);
                s += p0 + p1 + p2 + p3;
            }
            for (; k < cnt; k += 4) {
                int2 t0 = sh[wid][k + q];          // zero-padded entries safe
                float p0 = __int_as_float(t0.y);
                uint2 u0 = *(const uint2*)(h + (size_t)t0.x * H_CH + 4 * c);
                a0 += p0 * bflo(u0.x); a1 += p0 * bfhi(u0.x);
                a2 += p0 * bflo(u0.y); a3 += p0 * bfhi(u0.y);
                s += p0;
            }
        }
        a0 += __shfl_xor(a0, 16, 64); a0 += __shfl_xor(a0, 32, 64);
        a1 += __shfl_xor(a1, 16, 64); a1 += __shfl_xor(a1, 32, 64);
        a2 += __shfl_xor(a2, 16, 64); a2 += __shfl_xor(a2, 32, 64);
        a3 += __shfl_xor(a3, 16, 64); a3 += __shfl_xor(a3, 32, 64);
        s  += __shfl_xor(s, 16, 64);  s  += __shfl_xor(s, 32, 64);
        float invs = 1.f / (s + 1e-16f);
        if (q == 0) {
            ushort4 o;
            o.x = f2bf(fmaxf(a0 * invs + bv.x, 0.f));   // relu
            o.y = f2bf(fmaxf(a1 * invs + bv.y, 0.f));
            o.z = f2bf(fmaxf(a2 * invs + bv.z, 0.f));
            o.w = f2bf(fmaxf(a3 * invs + bv.w, 0.f));
            *(ushort4*)(out + (size_t)i * H_CH + 4 * c) = o;
        }
    }
}

// ---------------- GCN gather: r12's fastest-measured variant (42.9us) ----------------

template <bool RELU, bool BIASF>
__global__ __launch_bounds__(256) void gcn_gather(const unsigned short* __restrict__ h,
                                                  const int* __restrict__ offs,
                                                  const int* __restrict__ esrc,
                                                  const float* __restrict__ dinv,
                                                  const float* __restrict__ bias,
                                                  unsigned short* __restrict__ out, int n) {
    __shared__ int2 sh[4][64];
    int lane = threadIdx.x & 63;
    int wid  = threadIdx.x >> 6;
    int q = lane >> 4, c = lane & 15;
    int gw = (blockIdx.x * blockDim.x + threadIdx.x) >> 6;
    int nw = (gridDim.x * blockDim.x) >> 6;
    float4 bv = make_float4(0.f, 0.f, 0.f, 0.f);
    if (BIASF) bv = *(const float4*)(bias + 4 * c);
    for (int i = gw; i < n; i += nw) {
        int beg = offs[i], end = offs[i + 1];
        float a0 = 0.f, a1 = 0.f, a2 = 0.f, a3 = 0.f;
        for (int base = beg; base < end; base += 64) {
            int l = base + lane;
            int sj = 0; float wl = 0.f;
            if (l < end) { sj = esrc[l]; wl = dinv[sj]; }
            sh[wid][lane] = make_int2(sj, __float_as_int(wl));
            int cnt = min(64, end - base);
            int k = 0;
            for (; k + 16 <= cnt; k += 16) {
                int2 t0 = sh[wid][k + q];
                int2 t1 = sh[wid][k + 4 + q];
                int2 t2 = sh[wid][k + 8 + q];
                int2 t3 = sh[wid][k + 12 + q];
                float p0 = __int_as_float(t0.y), p1 = __int_as_float(t1.y);
                float p2 = __int_as_float(t2.y), p3 = __int_as_float(t3.y);
                uint2 u0 = *(const uint2*)(h + (size_t)t0.x * H_CH + 4 * c);
                uint2 u1 = *(const uint2*)(h + (size_t)t1.x * H_CH + 4 * c);
                uint2 u2 = *(const uint2*)(h + (size_t)t2.x * H_CH + 4 * c);
                uint2 u3 = *(const uint2*)(h + (size_t)t3.x * H_CH + 4 * c);
                a0 += p0 * bflo(u0.x); a1 += p0 * bfhi(u0.x);
                a2 += p0 * bflo(u0.y); a3 += p0 * bfhi(u0.y);
                a0 += p1 * bflo(u1.x); a1 += p1 * bfhi(u1.x);
                a2 += p1 * bflo(u1.y); a3 += p1 * bfhi(u1.y);
                a0 += p2 * bflo(u2.x); a1 += p2 * bfhi(u2.x);
                a2 += p2 * bflo(u2.y); a3 += p2 * bfhi(u2.y);
                a0 += p3 * bflo(u3.x); a1 += p3 * bfhi(u3.x);
                a2 += p3 * bflo(u3.y); a3 += p3 * bfhi(u3.y);
            }
            for (; k < cnt; k += 4) {
                int2 t0 = sh[wid][k + q];
                float p0 = __int_as_float(t0.y);
                uint2 u0 = *(const uint2*)(h + (size_t)t0.x * H_CH + 4 * c);
                a0 += p0 * bflo(u0.x); a1 += p0 * bfhi(u0.x);
                a2 += p0 * bflo(u0.y); a3 += p0 * bfhi(u0.y);
            }
        }
        a0 += __shfl_xor(a0, 16, 64); a0 += __shfl_xor(a0, 32, 64);
        a1 += __shfl_xor(a1, 16, 64); a1 += __shfl_xor(a1, 32, 64);
        a2 += __shfl_xor(a2, 16, 64); a2 += __shfl_xor(a2, 32, 64);
        a3 += __shfl_xor(a3, 16, 64); a3 += __shfl_xor(a3, 32, 64);
        float di = dinv[i];
        if (q == 0) {
            float v0 = a0 * di + bv.x, v1 = a1 * di + bv.y;
            float v2 = a2 * di + bv.z, v3 = a3 * di + bv.w;
            if (RELU) {
                v0 = fmaxf(v0, 0.f); v1 = fmaxf(v1, 0.f);
                v2 = fmaxf(v2, 0.f); v3 = fmaxf(v3, 0.f);
            }
            ushort4 o;
            o.x = f2bf(v0); o.y = f2bf(v1); o.z = f2bf(v2); o.w = f2bf(v3);
            *(ushort4*)(out + (size_t)i * H_CH + 4 * c) = o;
        }
    }
}

// ---------------- launch ----------------

extern "C" void kernel_launch(void* const* d_in, const int* in_sizes, int n_in,
                              void* d_out, int out_size, void* d_ws, size_t ws_size,
                              hipStream_t stream) {
    const float* x       = (const float*)d_in[0];
    const int*   ei      = (const int*)d_in[1];
    const float* W_gat   = (const float*)d_in[2];
    const float* att_src = (const float*)d_in[3];
    const float* att_dst = (const float*)d_in[4];
    const float* b_gat   = (const float*)d_in[5];
    const float* W1      = (const float*)d_in[6];
    const float* b1      = (const float*)d_in[7];
    const float* W2      = (const float*)d_in[8];
    const float* b2      = (const float*)d_in[9];
    float* out = (float*)d_out;

    const int N  = in_sizes[0] / IN_CH;
    const int E  = in_sizes[1] / 2;
    const int EP = E + N;
    const int NBK = (N + BKT - 1) / BKT;

    char* p = (char*)d_ws;
    auto alloc = [&](size_t bytes) -> void* {
        void* r = (void*)p;
        p += (bytes + 255) & ~(size_t)255;
        return r;
    };
    unsigned short* hbf  = (unsigned short*)alloc((size_t)N * H_CH * 2);  // gemm1/2 out
    unsigned short* hbfA = (unsigned short*)alloc((size_t)N * H_CH * 2);  // gat out / agg3
    unsigned short* hbf2 = (unsigned short*)alloc((size_t)N * H_CH * 2);  // layer2 gather out
    float* alpha_s = (float*)alloc((size_t)N * 4);
    float* alpha_d = (float*)alloc((size_t)N * 4);
    float* dinv    = (float*)alloc((size_t)N * 4);
    int*   offsets = (int*)alloc((size_t)(N + 1) * 4);
    int*   esrc    = (int*)alloc((size_t)EP * 4);
    int2*  pairs   = (int2*)alloc((size_t)EP * 8);
    int*   blkhist = (int*)alloc((size_t)PBLK * NBK * 4);
    int*   blkbase = (int*)alloc((size_t)PBLK * NBK * 4);
    int*   btot    = (int*)alloc((size_t)(NBK + 1) * 4);

    // CSR build (no global atomics, no memsets)
    passA<<<PBLK, PTHR, 0, stream>>>(ei, E, N, NBK, blkhist);
    passB1<<<NBK, PBLK, 0, stream>>>(blkhist, blkbase, btot, NBK);
    passC<<<PBLK, PTHR, 0, stream>>>(ei, E, N, NBK, btot, blkbase, pairs);
    passD<<<NBK, BKT, 0, stream>>>(pairs, btot, N, NBK, EP, esrc, offsets, dinv);

    // layer 1: GAT. MFMA gemm (fp32 in, wprep folded) -> bf16 h + fp32 alphas; gather
    mfma_gemm<IN_CH, true, true, false, float><<<512, 256, 0, stream>>>(
        x, W_gat, hbf, att_src, att_dst, alpha_s, alpha_d, nullptr, N);
    gat_gather<<<2048, 256, 0, stream>>>(hbf, offsets, esrc, alpha_s, alpha_d, b_gat, hbfA, N);

    // layer 2: GCN + relu. MFMA gemm (bf16 in) -> bf16 hbf; gather -> bf16 hbf2
    mfma_gemm<H_CH, false, true, false, unsigned short><<<512, 256, 0, stream>>>(
        hbfA, W1, hbf, nullptr, nullptr, nullptr, nullptr, nullptr, N);
    gcn_gather<true, true><<<2048, 256, 0, stream>>>(hbf, offsets, esrc, dinv, b1, hbf2, N);

    // layer 3: GCN reordered (linearity): agg3 = A_norm h2 (bf16), out = agg3 @ W2 + b2
    gcn_gather<false, false><<<2048, 256, 0, stream>>>(hbf2, offsets, esrc, dinv, nullptr,
                                                       hbfA, N);
    mfma_gemm<H_CH, false, false, true, unsigned short><<<512, 256, 0, stream>>>(
        hbfA, W2, out, nullptr, nullptr, nullptr, nullptr, b2, N);
}